// Round 14
// baseline (128.675 us; speedup 1.0000x reference)
//
#include <hip/hip_runtime.h>
#include <hip/hip_fp16.h>

#define NN 512          // N == M
#define DD 64           // feature dim
#define BIGF 1e10f
#define INV_LN2 1.44269504088896340736f
#define LN2 0.69314718055994530942f

// DP schedule (r8, proven): per batch 256 threads = 4 waves; thread t owns rows
// 2t, 2t+1; l = t&63, w = t>>6; off(t) = l + 80*w. At step s lane t does column
// c = s - off(t). S[s][t] = half2( delta[2t][c], delta[2t+1][c] ) / ln2.
#define W0 80
#define TOTM 800        // 50 full 16-step blocks
#define EPI 15          // +15 epilogue steps -> last step s = 814
#define SROWS 832       // >= 814 + 16 prefetch + 1

// ======================= Phase 1: MFMA delta -> schedule-order S (r13 verbatim) =======================
#define TS 128
#define HST 72          // LDS half-row stride (64 + 8 pad halves; 144 B rows)
#define LST 66          // Ls row stride (dwords)

typedef _Float16 v8h __attribute__((ext_vector_type(8)));
typedef float v4f __attribute__((ext_vector_type(4)));

__global__ __launch_bounds__(256, 2)
void delta_kernel(const float* __restrict__ A, const float* __restrict__ Bm,
                  unsigned* __restrict__ Sg)   // S dwords [b][SROWS][256]
{
  __shared__ __align__(16) char smem[191 * LST * 4];   // 50424 B: Ah|Bh, then Ls
  __shared__ float norms[2 * TS];                      // A-row (yy) | B-row (xx)
  _Float16* Ah = (_Float16*)smem;            // [TS][HST]  A rows (= DP columns j)
  _Float16* Bh = Ah + TS * HST;              // [TS][HST]  B rows (= DP rows i)
  unsigned* Ls = (unsigned*)smem;            // [191][LST] parallelogram re-stage
  _Float16* Lh = (_Float16*)smem;            // half view of Ls

  const int bz = blockIdx.z;
  const int u0 = blockIdx.y * TS;     // j tile base
  const int v0 = blockIdx.x * TS;     // i tile base
  const int bx = blockIdx.x;
  const int tid = threadIdx.x;
  const int T0 = v0 >> 1;

  // ---- stage + f32->f16 convert ----
  const float4* A4 = (const float4*)(A  + ((size_t)bz * NN + u0) * DD);
  const float4* B4 = (const float4*)(Bm + ((size_t)bz * NN + v0) * DD);
  #pragma unroll
  for (int q = 0; q < 8; ++q) {
    int idx = tid + 256 * q;          // 0..2047
    int r = idx >> 4, c4 = idx & 15;
    float4 va = A4[idx], vb = B4[idx];
    __half2 a01 = __floats2half2_rn(va.x, va.y);
    __half2 a23 = __floats2half2_rn(va.z, va.w);
    __half2 b01 = __floats2half2_rn(vb.x, vb.y);
    __half2 b23 = __floats2half2_rn(vb.z, vb.w);
    uint2 ua; ua.x = *(unsigned*)&a01; ua.y = *(unsigned*)&a23;
    uint2 ub; ub.x = *(unsigned*)&b01; ub.y = *(unsigned*)&b23;
    *(uint2*)&Ah[r * HST + 4 * c4] = ua;
    *(uint2*)&Bh[r * HST + 4 * c4] = ub;
  }
  __syncthreads();

  // ---- row norms from f16 values (consistent with MFMA dot) ----
  {
    const _Float16* row = (tid < TS) ? &Ah[tid * HST] : &Bh[(tid - TS) * HST];
    float s = 0.f;
    #pragma unroll
    for (int q = 0; q < 8; ++q) {
      v8h v = *(const v8h*)&row[8 * q];
      #pragma unroll
      for (int e = 0; e < 8; ++e) { float x = (float)v[e]; s = fmaf(x, x, s); }
    }
    norms[tid] = s;
  }

  // ---- MFMA: wave w covers j-strip [32w,32w+32) x all 128 i ----
  const int l = tid & 63, w = tid >> 6;
  const int la = l & 15, lb = l >> 4;

  v4f acc[2][8];
  #pragma unroll
  for (int jf = 0; jf < 2; ++jf)
    #pragma unroll
    for (int f = 0; f < 8; ++f) acc[jf][f] = (v4f){0.f, 0.f, 0.f, 0.f};

  #pragma unroll
  for (int kf = 0; kf < 2; ++kf) {
    v8h af0 = *(const v8h*)&Ah[(32 * w + la) * HST + 32 * kf + 8 * lb];
    v8h af1 = *(const v8h*)&Ah[(32 * w + 16 + la) * HST + 32 * kf + 8 * lb];
    #pragma unroll
    for (int f = 0; f < 8; ++f) {
      v8h bf = *(const v8h*)&Bh[(16 * f + la) * HST + 32 * kf + 8 * lb];
      acc[0][f] = __builtin_amdgcn_mfma_f32_16x16x32_f16(af0, bf, acc[0][f], 0, 0, 0);
      acc[1][f] = __builtin_amdgcn_mfma_f32_16x16x32_f16(af1, bf, acc[1][f], 0, 0, 0);
    }
  }
  __syncthreads();   // Ah/Bh dead; norms visible; Ls may overwrite

  // ---- epilogue: delta -> half -> Ls parallelogram (r8 layout) ----
  // D layout: col (i) = la, row (j) = 4*lb + reg
  #pragma unroll
  for (int jf = 0; jf < 2; ++jf) {
    #pragma unroll
    for (int r = 0; r < 4; ++r) {
      int jl = 32 * w + 16 * jf + 4 * lb + r;
      float yy = norms[jl];
      #pragma unroll
      for (int f = 0; f < 8; ++f) {
        int il = 16 * f + la;
        float xx = norms[TS + il];
        float d = fmaf(-2.f, acc[jf][f][r], xx + yy) * INV_LN2;
        int tl = il >> 1;
        int sl = jl + tl;                       // s_local in [0,191)
        Lh[(sl * LST + tl) * 2 + (il & 1)] = (_Float16)d;
      }
    }
  }
  __syncthreads();

  // ---- coalesced write-out: row rr -> global s = s_base + rr ----
  const int k = tid & 63;
  const int s_base = u0 + W0 * bx;
  unsigned* So = Sg + (size_t)bz * SROWS * 256 + T0 + k;
  for (int r0 = 0; r0 < 191; r0 += 4) {
    int rr = r0 + (tid >> 6);
    if (rr < 191 && (unsigned)(rr - k) < 128u)
      So[(size_t)(s_base + rr) * 256] = Ls[rr * LST + k];
  }
}

// ======================= Phase 2: DP with fused-hi softmin (shorter chain) =======================
__device__ __forceinline__ float exp2c(float d)
{
  float dc = fmaxf(d, -126.0f);
  float t = fmaf(dc, 8388608.0f, 1064992367.0f);   // (127-0.043)*2^23
  return __int_as_float((int)t);
}
__device__ __forceinline__ float log2a(float s)
{
  return fmaf((float)__float_as_int(s), 1.19209290e-7f, -126.957f);
}

__global__ __launch_bounds__(256, 1)
void dp_kernel(const __half2* __restrict__ S, float* __restrict__ loss)
{
  __shared__ float ring[4 * 32];     // per-wave boundary ring; row 0 stays BIG

  const int b = blockIdx.x;
  const int t = threadIdx.x;
  const int l = t & 63, w = t >> 6;
  const int off = l + W0 * w;

  if (t < 128) ring[t] = BIGF;
  __syncthreads();

  const bool is_u0 = ((l & 15) == 0) && (l != 0);   // lanes 16,32,48: row_bcast15 path
  const bool is_l0 = (l == 0);                      // wave boundary: SGPR ring path
  const bool isw   = (l == 63) && (w < 3);          // ring writer

  const __half2* Sb = S + (size_t)b * SROWS * 256 + t;

  float aL0 = BIGF, aL1 = BIGF;
  float nbprev = (t == 0) ? 0.f : BIGF;   // corner R[-1][-1] = 0 folded into init
  int c = -off;

  __half2 pf[16];
  #pragma unroll
  for (int q = 0; q < 16; ++q) pf[q] = Sb[(size_t)q * 256];

// lo = del.x + softmin(nbprev, nbU, aL0); hi = del.y + softmin(aL0, lo, aL1)
// hi fused: with u = del.x + m1 and s1 = lo's exp-sum, 2^(m2-lo) = s1*2^(m2-u),
// so hi = del.y + m2 - log2(2^(m2-aL0) + 2^(m2-aL1) + s1*2^(m2-u)) -- exact.
#define DP_STEP(SIDX)                                                          \
  {                                                                            \
    float2 del = __half22float2(pf[(SIDX) & 15]);                              \
    int shr = __builtin_amdgcn_update_dpp(__float_as_int(aL1),                 \
               __float_as_int(aL1), 0x111, 0xF, 0xF, false);                   \
    int bc  = __builtin_amdgcn_update_dpp(__float_as_int(aL1),                 \
               __float_as_int(aL1), 0x142, 0xF, 0xF, false);                   \
    float nbU = __int_as_float(shr);                                           \
    nbU = is_u0 ? __int_as_float(bc) : nbU;                                    \
    nbU = is_l0 ? srq : nbU;                                                   \
    /* lo: softmin(nbprev, nbU, aL0) + del.x (med3 trick: min term = 1.0) */   \
    float m1  = fminf(fminf(nbprev, nbU), aL0);                                \
    float md1 = __builtin_amdgcn_fmed3f(nbprev, nbU, aL0);                     \
    float M1  = fmaxf(fmaxf(nbprev, nbU), aL0);                                \
    float s1 = 1.0f + exp2c(m1 - md1) + exp2c(m1 - M1);                        \
    float u  = del.x + m1;                                                     \
    float lo = u - log2a(s1);                                                  \
    /* hi fused: m2 = min3(aL0, aL1, u) */                                     \
    float m2 = fminf(fminf(aL0, aL1), u);                                      \
    float f0 = exp2c(m2 - aL0);                                                \
    float f1 = exp2c(m2 - aL1);                                                \
    float fm = exp2c(m2 - u);                                                  \
    float s2 = fmaf(s1, fm, f0 + f1);                                          \
    float hi = (del.y + m2) - log2a(s2);                                       \
    bool valid = ((unsigned)c < 512u);                                         \
    lo = valid ? lo : BIGF;                                                    \
    hi = valid ? hi : BIGF;                                                    \
    nbprev = nbU; aL0 = lo; aL1 = hi;                                          \
    if (isw) ring[(w + 1) * 32 + (c & 31)] = hi;                               \
    pf[(SIDX) & 15] = Sb[(size_t)((SIDX) + 16) * 256];                         \
    ++c;                                                                       \
  }

  for (int sb = 0; sb < TOTM; sb += 16) {
    int c0 = sb - W0 * w;
    float ringv = ring[w * 32 + ((c0 + (l & 15)) & 31)];
    #pragma unroll
    for (int q = 0; q < 16; ++q) {
      float srq = __int_as_float(
          __builtin_amdgcn_readlane(__float_as_int(ringv), q));
      DP_STEP(sb + q)
    }
    __syncthreads();
  }
  { // epilogue: steps 800..814 (lane 255 finishes at c=511 exactly)
    int c0 = TOTM - W0 * w;
    float ringv = ring[w * 32 + ((c0 + (l & 15)) & 31)];
    #pragma unroll
    for (int q = 0; q < EPI; ++q) {
      float srq = __int_as_float(
          __builtin_amdgcn_readlane(__float_as_int(ringv), q));
      DP_STEP(TOTM + q)
    }
  }

  if (t == 255)
    loss[b] = aL1 * LN2;   // R[511][511]
}

// ======================= Fallback (round-1 kernel, tiny ws) =======================
#define DQ 16
#define YST 68

__device__ __forceinline__ void fb_step(
    const int d, const int t, const float4* __restrict__ xr, const float xx,
    const float* __restrict__ ylds,
    const float* __restrict__ a1, const float* __restrict__ a2,
    float* __restrict__ aw, float& myP1)
{
  const int j = d - t;
  const bool valid = (j >= 0) && (j < NN);
  float dd = 0.f;
  if (valid) {
    const float* yrow = &ylds[j * YST];
    float ax = 0.f, ay = 0.f, az = 0.f, aww = 0.f;
    #pragma unroll
    for (int k = 0; k < DQ; ++k) {
      float4 v = *(const float4*)(yrow + 4 * k);
      ax  = fmaf(xr[k].x, v.x, ax);
      ay  = fmaf(xr[k].y, v.y, ay);
      az  = fmaf(xr[k].z, v.z, az);
      aww = fmaf(xr[k].w, v.w, aww);
    }
    float dot = (ax + ay) + (az + aww);
    dd = fmaf(-2.f, dot, xx + yrow[DD]);
  }
  float p1m1 = a1[t];
  float p2m1 = a2[t];
  if (t == 0) p2m1 = (d == 0) ? 0.f : BIGF;
  float m = fminf(fminf(p2m1, p1m1), myP1);
  float s = __expf(m - p2m1) + __expf(m - p1m1) + __expf(m - myP1);
  float sm = m - __logf(s);
  float cur = valid ? (dd + sm) : BIGF;
  aw[t + 1] = cur;
  myP1 = cur;
  __syncthreads();
}

__global__ __launch_bounds__(512, 2)
void dtw_fallback_kernel(const float* __restrict__ X, const float* __restrict__ Y,
                         float* __restrict__ loss)
{
  __shared__ float ylds[NN * YST];
  __shared__ float diag[3][NN + 1];

  const int b = blockIdx.x;
  const int t = threadIdx.x;

  const float4* Y4 = (const float4*)(Y + (size_t)b * NN * DD);
  for (int idx = t; idx < NN * DQ; idx += NN) {
    float4 v = Y4[idx];
    *(float4*)&ylds[(idx >> 4) * YST + (idx & 15) * 4] = v;
  }
  diag[0][t + 1] = BIGF; diag[1][t + 1] = BIGF; diag[2][t + 1] = BIGF;
  if (t == 0) { diag[0][0] = BIGF; diag[1][0] = BIGF; diag[2][0] = BIGF; }
  __syncthreads();

  float4 xr[DQ];
  float xx = 0.f;
  const float4* X4 = (const float4*)(X + (size_t)b * NN * DD + (size_t)t * DD);
  #pragma unroll
  for (int k = 0; k < DQ; ++k) {
    float4 v = X4[k];
    xr[k] = v;
    xx += v.x * v.x + v.y * v.y + v.z * v.z + v.w * v.w;
  }
  {
    float s = 0.f;
    const float* yrow = &ylds[t * YST];
    #pragma unroll
    for (int k = 0; k < DQ; ++k) {
      float4 v = *(const float4*)(yrow + 4 * k);
      s += v.x * v.x + v.y * v.y + v.z * v.z + v.w * v.w;
    }
    ylds[t * YST + DD] = s;
  }
  __syncthreads();

  float myP1 = BIGF;
  for (int dbase = 0; dbase < 2 * NN - 1; dbase += 3) {
    fb_step(dbase,     t, xr, xx, ylds, diag[2], diag[1], diag[0], myP1);
    fb_step(dbase + 1, t, xr, xx, ylds, diag[0], diag[2], diag[1], myP1);
    fb_step(dbase + 2, t, xr, xx, ylds, diag[1], diag[0], diag[2], myP1);
  }
  if (t == NN - 1) loss[b] = myP1;
}

// ======================= mean =======================
__global__ void mean_kernel(const float* __restrict__ loss, float* __restrict__ out, int B)
{
  const int t = threadIdx.x;
  float v = (t < B) ? loss[t] : 0.f;
  #pragma unroll
  for (int off = 32; off; off >>= 1) v += __shfl_down(v, off);
  if (t == 0) out[0] = v / (float)B;
}

extern "C" void kernel_launch(void* const* d_in, const int* in_sizes, int n_in,
                              void* d_out, int out_size, void* d_ws, size_t ws_size,
                              hipStream_t stream)
{
  const float* X = (const float*)d_in[0];   // input  (x, DP rows i)
  const float* Y = (const float*)d_in[1];   // target (y, DP cols j)
  float* out = (float*)d_out;
  float* ws  = (float*)d_ws;

  const int B = in_sizes[0] / (NN * DD);    // 64

  const size_t S_bytes = (size_t)B * SROWS * 256 * 4;
  const size_t need = S_bytes + 256;

  if (ws_size >= need) {
    float*    loss = ws;                    // B floats
    unsigned* Sg   = (unsigned*)(ws + 64);  // 256B offset, [b][SROWS][256] half2
    // A = Y (j rows), B = X (i rows)
    delta_kernel<<<dim3(NN / TS, NN / TS, B), 256, 0, stream>>>(Y, X, Sg);
    dp_kernel<<<B, 256, 0, stream>>>((const __half2*)Sg, loss);
    mean_kernel<<<1, 64, 0, stream>>>(loss, out, B);
  } else {
    dtw_fallback_kernel<<<B, NN, 0, stream>>>(X, Y, ws);
    mean_kernel<<<1, 64, 0, stream>>>(ws, out, B);
  }
}

// Round 15
// 117.032 us; speedup vs baseline: 1.0995x; 1.0995x over previous
//
#include <hip/hip_runtime.h>
#include <hip/hip_fp16.h>

#define NN 512          // N == M
#define DD 64           // feature dim
#define BIGF 1e10f
#define INV_LN2 1.44269504088896340736f
#define LN2 0.69314718055994530942f

// DP schedule (r8, proven): per batch 256 threads = 4 waves; thread t owns rows
// 2t, 2t+1; l = t&63, w = t>>6; off(t) = l + 80*w. At step s lane t does column
// c = s - off(t). S[s][t] = half2( delta[2t][c], delta[2t+1][c] ) / ln2.
#define W0 80
#define TOTM 800        // 50 full 16-step blocks
#define EPI 15          // +15 epilogue steps -> last step s = 814
#define SROWS 832       // >= 814 + 16 prefetch + 1

// ======================= Phase 1: MFMA delta -> schedule-order S (r13 verbatim) =======================
#define TS 128
#define HST 72          // LDS half-row stride (64 + 8 pad halves; 144 B rows)
#define LST 66          // Ls row stride (dwords)

typedef _Float16 v8h __attribute__((ext_vector_type(8)));
typedef float v4f __attribute__((ext_vector_type(4)));

__global__ __launch_bounds__(256, 2)
void delta_kernel(const float* __restrict__ A, const float* __restrict__ Bm,
                  unsigned* __restrict__ Sg)   // S dwords [b][SROWS][256]
{
  __shared__ __align__(16) char smem[191 * LST * 4];   // 50424 B: Ah|Bh, then Ls
  __shared__ float norms[2 * TS];                      // A-row (yy) | B-row (xx)
  _Float16* Ah = (_Float16*)smem;            // [TS][HST]  A rows (= DP columns j)
  _Float16* Bh = Ah + TS * HST;              // [TS][HST]  B rows (= DP rows i)
  unsigned* Ls = (unsigned*)smem;            // [191][LST] parallelogram re-stage
  _Float16* Lh = (_Float16*)smem;            // half view of Ls

  const int bz = blockIdx.z;
  const int u0 = blockIdx.y * TS;     // j tile base
  const int v0 = blockIdx.x * TS;     // i tile base
  const int bx = blockIdx.x;
  const int tid = threadIdx.x;
  const int T0 = v0 >> 1;

  // ---- stage + f32->f16 convert ----
  const float4* A4 = (const float4*)(A  + ((size_t)bz * NN + u0) * DD);
  const float4* B4 = (const float4*)(Bm + ((size_t)bz * NN + v0) * DD);
  #pragma unroll
  for (int q = 0; q < 8; ++q) {
    int idx = tid + 256 * q;          // 0..2047
    int r = idx >> 4, c4 = idx & 15;
    float4 va = A4[idx], vb = B4[idx];
    __half2 a01 = __floats2half2_rn(va.x, va.y);
    __half2 a23 = __floats2half2_rn(va.z, va.w);
    __half2 b01 = __floats2half2_rn(vb.x, vb.y);
    __half2 b23 = __floats2half2_rn(vb.z, vb.w);
    uint2 ua; ua.x = *(unsigned*)&a01; ua.y = *(unsigned*)&a23;
    uint2 ub; ub.x = *(unsigned*)&b01; ub.y = *(unsigned*)&b23;
    *(uint2*)&Ah[r * HST + 4 * c4] = ua;
    *(uint2*)&Bh[r * HST + 4 * c4] = ub;
  }
  __syncthreads();

  // ---- row norms from f16 values (consistent with MFMA dot) ----
  {
    const _Float16* row = (tid < TS) ? &Ah[tid * HST] : &Bh[(tid - TS) * HST];
    float s = 0.f;
    #pragma unroll
    for (int q = 0; q < 8; ++q) {
      v8h v = *(const v8h*)&row[8 * q];
      #pragma unroll
      for (int e = 0; e < 8; ++e) { float x = (float)v[e]; s = fmaf(x, x, s); }
    }
    norms[tid] = s;
  }

  // ---- MFMA: wave w covers j-strip [32w,32w+32) x all 128 i ----
  const int l = tid & 63, w = tid >> 6;
  const int la = l & 15, lb = l >> 4;

  v4f acc[2][8];
  #pragma unroll
  for (int jf = 0; jf < 2; ++jf)
    #pragma unroll
    for (int f = 0; f < 8; ++f) acc[jf][f] = (v4f){0.f, 0.f, 0.f, 0.f};

  #pragma unroll
  for (int kf = 0; kf < 2; ++kf) {
    v8h af0 = *(const v8h*)&Ah[(32 * w + la) * HST + 32 * kf + 8 * lb];
    v8h af1 = *(const v8h*)&Ah[(32 * w + 16 + la) * HST + 32 * kf + 8 * lb];
    #pragma unroll
    for (int f = 0; f < 8; ++f) {
      v8h bf = *(const v8h*)&Bh[(16 * f + la) * HST + 32 * kf + 8 * lb];
      acc[0][f] = __builtin_amdgcn_mfma_f32_16x16x32_f16(af0, bf, acc[0][f], 0, 0, 0);
      acc[1][f] = __builtin_amdgcn_mfma_f32_16x16x32_f16(af1, bf, acc[1][f], 0, 0, 0);
    }
  }
  __syncthreads();   // Ah/Bh dead; norms visible; Ls may overwrite

  // ---- epilogue: delta -> half -> Ls parallelogram (r8 layout) ----
  // D layout: col (i) = la, row (j) = 4*lb + reg
  #pragma unroll
  for (int jf = 0; jf < 2; ++jf) {
    #pragma unroll
    for (int r = 0; r < 4; ++r) {
      int jl = 32 * w + 16 * jf + 4 * lb + r;
      float yy = norms[jl];
      #pragma unroll
      for (int f = 0; f < 8; ++f) {
        int il = 16 * f + la;
        float xx = norms[TS + il];
        float d = fmaf(-2.f, acc[jf][f][r], xx + yy) * INV_LN2;
        int tl = il >> 1;
        int sl = jl + tl;                       // s_local in [0,191)
        Lh[(sl * LST + tl) * 2 + (il & 1)] = (_Float16)d;
      }
    }
  }
  __syncthreads();

  // ---- coalesced write-out: row rr -> global s = s_base + rr ----
  const int k = tid & 63;
  const int s_base = u0 + W0 * bx;
  unsigned* So = Sg + (size_t)bz * SROWS * 256 + T0 + k;
  for (int r0 = 0; r0 < 191; r0 += 4) {
    int rr = r0 + (tid >> 6);
    if (rr < 191 && (unsigned)(rr - k) < 128u)
      So[(size_t)(s_base + rr) * 256] = Ls[rr * LST + k];
  }
}

// ======================= Phase 2: r8 DP + named prefetch regs + min3/max3 asm =======================
__device__ __forceinline__ float min3f(float a, float b, float c)
{
  float r;
  asm("v_min3_f32 %0, %1, %2, %3" : "=v"(r) : "v"(a), "v"(b), "v"(c));
  return r;
}
__device__ __forceinline__ float max3f(float a, float b, float c)
{
  float r;
  asm("v_max3_f32 %0, %1, %2, %3" : "=v"(r) : "v"(a), "v"(b), "v"(c));
  return r;
}

__device__ __forceinline__ float softmin_fast(float a, float b, float c)
{
  float m  = min3f(a, b, c);
  float md = __builtin_amdgcn_fmed3f(a, b, c);
  float M  = max3f(a, b, c);
  float d1 = fmaxf(m - md, -126.0f);
  float d2 = fmaxf(m - M,  -126.0f);
  float t1 = fmaf(d1, 8388608.0f, 1064992367.0f);   // (127-0.043)*2^23
  float t2 = fmaf(d2, 8388608.0f, 1064992367.0f);
  float e1 = __int_as_float((int)t1);
  float e2 = __int_as_float((int)t2);
  float s = 1.0f + e1 + e2;
  float lg = fmaf((float)__float_as_int(s), 1.19209290e-7f, -126.957f);
  return m - lg;
}

__global__ __launch_bounds__(256, 1)
void dp_kernel(const __half2* __restrict__ S, float* __restrict__ loss)
{
  __shared__ float ring[4 * 32];     // per-wave boundary ring; row 0 stays BIG

  const int b = blockIdx.x;
  const int t = threadIdx.x;
  const int l = t & 63, w = t >> 6;
  const int off = l + W0 * w;

  if (t < 128) ring[t] = BIGF;
  __syncthreads();

  const bool is_u0 = ((l & 15) == 0) && (l != 0);   // lanes 16,32,48: row_bcast15 path
  const bool is_l0 = (l == 0);                      // wave boundary: SGPR ring path
  const bool isw   = (l == 63) && (w < 3);          // ring writer

  const __half2* Sb = S + (size_t)b * SROWS * 256 + t;

  float aL0 = BIGF, aL1 = BIGF, hprev = BIGF;
  float nbprev = (t == 0) ? 0.f : BIGF;   // corner R[-1][-1] = 0 folded into init
  int c = -off;

  // 16 NAMED prefetch registers (rule #20: arrays get demoted; named vars stay VGPR)
  __half2 pf0  = Sb[(size_t)0  * 256], pf1  = Sb[(size_t)1  * 256];
  __half2 pf2  = Sb[(size_t)2  * 256], pf3  = Sb[(size_t)3  * 256];
  __half2 pf4  = Sb[(size_t)4  * 256], pf5  = Sb[(size_t)5  * 256];
  __half2 pf6  = Sb[(size_t)6  * 256], pf7  = Sb[(size_t)7  * 256];
  __half2 pf8  = Sb[(size_t)8  * 256], pf9  = Sb[(size_t)9  * 256];
  __half2 pf10 = Sb[(size_t)10 * 256], pf11 = Sb[(size_t)11 * 256];
  __half2 pf12 = Sb[(size_t)12 * 256], pf13 = Sb[(size_t)13 * 256];
  __half2 pf14 = Sb[(size_t)14 * 256], pf15 = Sb[(size_t)15 * 256];

#define DP_STEP(SIDX, Q, PF)                                                   \
  {                                                                            \
    float srq = __int_as_float(                                                \
        __builtin_amdgcn_readlane(__float_as_int(ringv), (Q)));                \
    float2 del = __half22float2(PF);                                           \
    int shr = __builtin_amdgcn_update_dpp(__float_as_int(hprev),               \
               __float_as_int(hprev), 0x111, 0xF, 0xF, false);                 \
    int bc  = __builtin_amdgcn_update_dpp(__float_as_int(hprev),               \
               __float_as_int(hprev), 0x142, 0xF, 0xF, false);                 \
    float nbU = __int_as_float(shr);                                           \
    nbU = is_u0 ? __int_as_float(bc) : nbU;                                    \
    nbU = is_l0 ? srq : nbU;                                                   \
    float lo = del.x + softmin_fast(nbprev, nbU, aL0);                         \
    float hi = del.y + softmin_fast(aL0, lo, aL1);                             \
    bool valid = ((unsigned)c < 512u);                                         \
    lo = valid ? lo : BIGF;                                                    \
    hi = valid ? hi : BIGF;                                                    \
    nbprev = nbU; aL0 = lo; aL1 = hi; hprev = hi;                              \
    if (isw) ring[(w + 1) * 32 + (c & 31)] = hi;                               \
    PF = Sb[(size_t)((SIDX) + 16) * 256];                                      \
    ++c;                                                                       \
  }

  for (int sb = 0; sb < TOTM; sb += 16) {
    int c0 = sb - W0 * w;
    float ringv = ring[w * 32 + ((c0 + (l & 15)) & 31)];
    DP_STEP(sb + 0,  0,  pf0)  DP_STEP(sb + 1,  1,  pf1)
    DP_STEP(sb + 2,  2,  pf2)  DP_STEP(sb + 3,  3,  pf3)
    DP_STEP(sb + 4,  4,  pf4)  DP_STEP(sb + 5,  5,  pf5)
    DP_STEP(sb + 6,  6,  pf6)  DP_STEP(sb + 7,  7,  pf7)
    DP_STEP(sb + 8,  8,  pf8)  DP_STEP(sb + 9,  9,  pf9)
    DP_STEP(sb + 10, 10, pf10) DP_STEP(sb + 11, 11, pf11)
    DP_STEP(sb + 12, 12, pf12) DP_STEP(sb + 13, 13, pf13)
    DP_STEP(sb + 14, 14, pf14) DP_STEP(sb + 15, 15, pf15)
    __syncthreads();
  }
  { // epilogue: steps 800..814 (lane 255 finishes at c=511 exactly)
    int c0 = TOTM - W0 * w;
    float ringv = ring[w * 32 + ((c0 + (l & 15)) & 31)];
    DP_STEP(TOTM + 0,  0,  pf0)  DP_STEP(TOTM + 1,  1,  pf1)
    DP_STEP(TOTM + 2,  2,  pf2)  DP_STEP(TOTM + 3,  3,  pf3)
    DP_STEP(TOTM + 4,  4,  pf4)  DP_STEP(TOTM + 5,  5,  pf5)
    DP_STEP(TOTM + 6,  6,  pf6)  DP_STEP(TOTM + 7,  7,  pf7)
    DP_STEP(TOTM + 8,  8,  pf8)  DP_STEP(TOTM + 9,  9,  pf9)
    DP_STEP(TOTM + 10, 10, pf10) DP_STEP(TOTM + 11, 11, pf11)
    DP_STEP(TOTM + 12, 12, pf12) DP_STEP(TOTM + 13, 13, pf13)
    DP_STEP(TOTM + 14, 14, pf14)
  }

  if (t == 255)
    loss[b] = aL1 * LN2;   // R[511][511]
}

// ======================= Fallback (round-1 kernel, tiny ws) =======================
#define DQ 16
#define YST 68

__device__ __forceinline__ void fb_step(
    const int d, const int t, const float4* __restrict__ xr, const float xx,
    const float* __restrict__ ylds,
    const float* __restrict__ a1, const float* __restrict__ a2,
    float* __restrict__ aw, float& myP1)
{
  const int j = d - t;
  const bool valid = (j >= 0) && (j < NN);
  float dd = 0.f;
  if (valid) {
    const float* yrow = &ylds[j * YST];
    float ax = 0.f, ay = 0.f, az = 0.f, aww = 0.f;
    #pragma unroll
    for (int k = 0; k < DQ; ++k) {
      float4 v = *(const float4*)(yrow + 4 * k);
      ax  = fmaf(xr[k].x, v.x, ax);
      ay  = fmaf(xr[k].y, v.y, ay);
      az  = fmaf(xr[k].z, v.z, az);
      aww = fmaf(xr[k].w, v.w, aww);
    }
    float dot = (ax + ay) + (az + aww);
    dd = fmaf(-2.f, dot, xx + yrow[DD]);
  }
  float p1m1 = a1[t];
  float p2m1 = a2[t];
  if (t == 0) p2m1 = (d == 0) ? 0.f : BIGF;
  float m = fminf(fminf(p2m1, p1m1), myP1);
  float s = __expf(m - p2m1) + __expf(m - p1m1) + __expf(m - myP1);
  float sm = m - __logf(s);
  float cur = valid ? (dd + sm) : BIGF;
  aw[t + 1] = cur;
  myP1 = cur;
  __syncthreads();
}

__global__ __launch_bounds__(512, 2)
void dtw_fallback_kernel(const float* __restrict__ X, const float* __restrict__ Y,
                         float* __restrict__ loss)
{
  __shared__ float ylds[NN * YST];
  __shared__ float diag[3][NN + 1];

  const int b = blockIdx.x;
  const int t = threadIdx.x;

  const float4* Y4 = (const float4*)(Y + (size_t)b * NN * DD);
  for (int idx = t; idx < NN * DQ; idx += NN) {
    float4 v = Y4[idx];
    *(float4*)&ylds[(idx >> 4) * YST + (idx & 15) * 4] = v;
  }
  diag[0][t + 1] = BIGF; diag[1][t + 1] = BIGF; diag[2][t + 1] = BIGF;
  if (t == 0) { diag[0][0] = BIGF; diag[1][0] = BIGF; diag[2][0] = BIGF; }
  __syncthreads();

  float4 xr[DQ];
  float xx = 0.f;
  const float4* X4 = (const float4*)(X + (size_t)b * NN * DD + (size_t)t * DD);
  #pragma unroll
  for (int k = 0; k < DQ; ++k) {
    float4 v = X4[k];
    xr[k] = v;
    xx += v.x * v.x + v.y * v.y + v.z * v.z + v.w * v.w;
  }
  {
    float s = 0.f;
    const float* yrow = &ylds[t * YST];
    #pragma unroll
    for (int k = 0; k < DQ; ++k) {
      float4 v = *(const float4*)(yrow + 4 * k);
      s += v.x * v.x + v.y * v.y + v.z * v.z + v.w * v.w;
    }
    ylds[t * YST + DD] = s;
  }
  __syncthreads();

  float myP1 = BIGF;
  for (int dbase = 0; dbase < 2 * NN - 1; dbase += 3) {
    fb_step(dbase,     t, xr, xx, ylds, diag[2], diag[1], diag[0], myP1);
    fb_step(dbase + 1, t, xr, xx, ylds, diag[0], diag[2], diag[1], myP1);
    fb_step(dbase + 2, t, xr, xx, ylds, diag[1], diag[0], diag[2], myP1);
  }
  if (t == NN - 1) loss[b] = myP1;
}

// ======================= mean =======================
__global__ void mean_kernel(const float* __restrict__ loss, float* __restrict__ out, int B)
{
  const int t = threadIdx.x;
  float v = (t < B) ? loss[t] : 0.f;
  #pragma unroll
  for (int off = 32; off; off >>= 1) v += __shfl_down(v, off);
  if (t == 0) out[0] = v / (float)B;
}

extern "C" void kernel_launch(void* const* d_in, const int* in_sizes, int n_in,
                              void* d_out, int out_size, void* d_ws, size_t ws_size,
                              hipStream_t stream)
{
  const float* X = (const float*)d_in[0];   // input  (x, DP rows i)
  const float* Y = (const float*)d_in[1];   // target (y, DP cols j)
  float* out = (float*)d_out;
  float* ws  = (float*)d_ws;

  const int B = in_sizes[0] / (NN * DD);    // 64

  const size_t S_bytes = (size_t)B * SROWS * 256 * 4;
  const size_t need = S_bytes + 256;

  if (ws_size >= need) {
    float*    loss = ws;                    // B floats
    unsigned* Sg   = (unsigned*)(ws + 64);  // 256B offset, [b][SROWS][256] half2
    // A = Y (j rows), B = X (i rows)
    delta_kernel<<<dim3(NN / TS, NN / TS, B), 256, 0, stream>>>(Y, X, Sg);
    dp_kernel<<<B, 256, 0, stream>>>((const __half2*)Sg, loss);
    mean_kernel<<<1, 64, 0, stream>>>(loss, out, B);
  } else {
    dtw_fallback_kernel<<<B, NN, 0, stream>>>(X, Y, ws);
    mean_kernel<<<1, 64, 0, stream>>>(ws, out, B);
  }
}

// Round 17
// 115.053 us; speedup vs baseline: 1.1184x; 1.0172x over previous
//
#include <hip/hip_runtime.h>
#include <hip/hip_fp16.h>

#define NN 512          // N == M
#define DD 64           // feature dim
#define BIGF 1e10f
#define INV_LN2 1.44269504088896340736f
#define LN2 0.69314718055994530942f

// DP schedule (r8, proven): per batch 256 threads = 4 waves; thread t owns rows
// 2t, 2t+1; l = t&63, w = t>>6; off(t) = l + 80*w. At step s lane t does column
// c = s - off(t). S[s][t] = half2( delta[2t][c], delta[2t+1][c] ) / ln2.
#define W0 80
#define TOTM 800        // 50 full 16-step blocks
#define EPI 15          // +15 epilogue steps -> last step s = 814
#define SROWS 832       // >= 814 + 16 prefetch + 1

// ======================= Phase 1: MFMA delta -> schedule-order S (r13 verbatim) =======================
#define TS 128
#define HST 72          // LDS half-row stride (64 + 8 pad halves; 144 B rows)
#define LST 66          // Ls row stride (dwords)

typedef _Float16 v8h __attribute__((ext_vector_type(8)));
typedef float v4f __attribute__((ext_vector_type(4)));

__global__ __launch_bounds__(256, 2)
void delta_kernel(const float* __restrict__ A, const float* __restrict__ Bm,
                  unsigned* __restrict__ Sg)   // S dwords [b][SROWS][256]
{
  __shared__ __align__(16) char smem[191 * LST * 4];   // 50424 B: Ah|Bh, then Ls
  __shared__ float norms[2 * TS];                      // A-row (yy) | B-row (xx)
  _Float16* Ah = (_Float16*)smem;            // [TS][HST]  A rows (= DP columns j)
  _Float16* Bh = Ah + TS * HST;              // [TS][HST]  B rows (= DP rows i)
  unsigned* Ls = (unsigned*)smem;            // [191][LST] parallelogram re-stage
  _Float16* Lh = (_Float16*)smem;            // half view of Ls

  const int bz = blockIdx.z;
  const int u0 = blockIdx.y * TS;     // j tile base
  const int v0 = blockIdx.x * TS;     // i tile base
  const int bx = blockIdx.x;
  const int tid = threadIdx.x;
  const int T0 = v0 >> 1;

  // ---- stage + f32->f16 convert ----
  const float4* A4 = (const float4*)(A  + ((size_t)bz * NN + u0) * DD);
  const float4* B4 = (const float4*)(Bm + ((size_t)bz * NN + v0) * DD);
  #pragma unroll
  for (int q = 0; q < 8; ++q) {
    int idx = tid + 256 * q;          // 0..2047
    int r = idx >> 4, c4 = idx & 15;
    float4 va = A4[idx], vb = B4[idx];
    __half2 a01 = __floats2half2_rn(va.x, va.y);
    __half2 a23 = __floats2half2_rn(va.z, va.w);
    __half2 b01 = __floats2half2_rn(vb.x, vb.y);
    __half2 b23 = __floats2half2_rn(vb.z, vb.w);
    uint2 ua; ua.x = *(unsigned*)&a01; ua.y = *(unsigned*)&a23;
    uint2 ub; ub.x = *(unsigned*)&b01; ub.y = *(unsigned*)&b23;
    *(uint2*)&Ah[r * HST + 4 * c4] = ua;
    *(uint2*)&Bh[r * HST + 4 * c4] = ub;
  }
  __syncthreads();

  // ---- row norms from f16 values (consistent with MFMA dot) ----
  {
    const _Float16* row = (tid < TS) ? &Ah[tid * HST] : &Bh[(tid - TS) * HST];
    float s = 0.f;
    #pragma unroll
    for (int q = 0; q < 8; ++q) {
      v8h v = *(const v8h*)&row[8 * q];
      #pragma unroll
      for (int e = 0; e < 8; ++e) { float x = (float)v[e]; s = fmaf(x, x, s); }
    }
    norms[tid] = s;
  }

  // ---- MFMA: wave w covers j-strip [32w,32w+32) x all 128 i ----
  const int l = tid & 63, w = tid >> 6;
  const int la = l & 15, lb = l >> 4;

  v4f acc[2][8];
  #pragma unroll
  for (int jf = 0; jf < 2; ++jf)
    #pragma unroll
    for (int f = 0; f < 8; ++f) acc[jf][f] = (v4f){0.f, 0.f, 0.f, 0.f};

  #pragma unroll
  for (int kf = 0; kf < 2; ++kf) {
    v8h af0 = *(const v8h*)&Ah[(32 * w + la) * HST + 32 * kf + 8 * lb];
    v8h af1 = *(const v8h*)&Ah[(32 * w + 16 + la) * HST + 32 * kf + 8 * lb];
    #pragma unroll
    for (int f = 0; f < 8; ++f) {
      v8h bf = *(const v8h*)&Bh[(16 * f + la) * HST + 32 * kf + 8 * lb];
      acc[0][f] = __builtin_amdgcn_mfma_f32_16x16x32_f16(af0, bf, acc[0][f], 0, 0, 0);
      acc[1][f] = __builtin_amdgcn_mfma_f32_16x16x32_f16(af1, bf, acc[1][f], 0, 0, 0);
    }
  }
  __syncthreads();   // Ah/Bh dead; norms visible; Ls may overwrite

  // ---- epilogue: delta -> half -> Ls parallelogram (r8 layout) ----
  // D layout: col (i) = la, row (j) = 4*lb + reg
  #pragma unroll
  for (int jf = 0; jf < 2; ++jf) {
    #pragma unroll
    for (int r = 0; r < 4; ++r) {
      int jl = 32 * w + 16 * jf + 4 * lb + r;
      float yy = norms[jl];
      #pragma unroll
      for (int f = 0; f < 8; ++f) {
        int il = 16 * f + la;
        float xx = norms[TS + il];
        float d = fmaf(-2.f, acc[jf][f][r], xx + yy) * INV_LN2;
        int tl = il >> 1;
        int sl = jl + tl;                       // s_local in [0,191)
        Lh[(sl * LST + tl) * 2 + (il & 1)] = (_Float16)d;
      }
    }
  }
  __syncthreads();

  // ---- coalesced write-out: row rr -> global s = s_base + rr ----
  const int k = tid & 63;
  const int s_base = u0 + W0 * bx;
  unsigned* So = Sg + (size_t)bz * SROWS * 256 + T0 + k;
  for (int r0 = 0; r0 < 191; r0 += 4) {
    int rr = r0 + (tid >> 6);
    if (rr < 191 && (unsigned)(rr - k) < 128u)
      So[(size_t)(s_base + rr) * 256] = Ls[rr * LST + k];
  }
}

// ======================= Phase 2: r13 dp_kernel + raw lgkmcnt barrier (T4) =======================
__device__ __forceinline__ float softmin_fast(float a, float b, float c)
{
  float m  = fminf(fminf(a, b), c);
  float md = __builtin_amdgcn_fmed3f(a, b, c);
  float M  = fmaxf(fmaxf(a, b), c);
  float d1 = fmaxf(m - md, -126.0f);
  float d2 = fmaxf(m - M,  -126.0f);
  float t1 = fmaf(d1, 8388608.0f, 1064992367.0f);   // (127-0.043)*2^23
  float t2 = fmaf(d2, 8388608.0f, 1064992367.0f);
  float e1 = __int_as_float((int)t1);
  float e2 = __int_as_float((int)t2);
  float s = 1.0f + e1 + e2;
  float lg = fmaf((float)__float_as_int(s), 1.19209290e-7f, -126.957f);
  return m - lg;
}

__global__ __launch_bounds__(256, 1)
void dp_kernel(const __half2* __restrict__ S, float* __restrict__ loss)
{
  __shared__ float ring[4 * 32];     // per-wave boundary ring; row 0 stays BIG

  const int b = blockIdx.x;
  const int t = threadIdx.x;
  const int l = t & 63, w = t >> 6;
  const int off = l + W0 * w;

  if (t < 128) ring[t] = BIGF;
  __syncthreads();

  const bool is_u0 = ((l & 15) == 0) && (l != 0);   // lanes 16,32,48: row_bcast15 path
  const bool is_l0 = (l == 0);                      // wave boundary: SGPR ring path
  const bool isw   = (l == 63) && (w < 3);          // ring writer

  const __half2* Sb = S + (size_t)b * SROWS * 256 + t;

  float aL0 = BIGF, aL1 = BIGF, hprev = BIGF;
  float nbprev = (t == 0) ? 0.f : BIGF;   // corner R[-1][-1] = 0 folded into init
  int c = -off;

  __half2 pf[16];
  #pragma unroll
  for (int q = 0; q < 16; ++q) pf[q] = Sb[(size_t)q * 256];

#define DP_STEP(SIDX)                                                          \
  {                                                                            \
    float2 del = __half22float2(pf[(SIDX) & 15]);                              \
    int shr = __builtin_amdgcn_update_dpp(__float_as_int(hprev),               \
               __float_as_int(hprev), 0x111, 0xF, 0xF, false);                 \
    int bc  = __builtin_amdgcn_update_dpp(__float_as_int(hprev),               \
               __float_as_int(hprev), 0x142, 0xF, 0xF, false);                 \
    float nbU = __int_as_float(shr);                                           \
    nbU = is_u0 ? __int_as_float(bc) : nbU;                                    \
    nbU = is_l0 ? srq : nbU;                                                   \
    float lo = del.x + softmin_fast(nbprev, nbU, aL0);                         \
    float hi = del.y + softmin_fast(aL0, lo, aL1);                             \
    bool valid = ((unsigned)c < 512u);                                         \
    lo = valid ? lo : BIGF;                                                    \
    hi = valid ? hi : BIGF;                                                    \
    nbprev = nbU; aL0 = lo; aL1 = hi; hprev = hi;                              \
    if (isw) ring[(w + 1) * 32 + (c & 31)] = hi;                               \
    pf[(SIDX) & 15] = Sb[(size_t)((SIDX) + 16) * 256];                         \
    ++c;                                                                       \
  }

  for (int sb = 0; sb < TOTM; sb += 16) {
    int c0 = sb - W0 * w;
    float ringv = ring[w * 32 + ((c0 + (l & 15)) & 31)];
    #pragma unroll
    for (int q = 0; q < 16; ++q) {
      float srq = __int_as_float(
          __builtin_amdgcn_readlane(__float_as_int(ringv), q));
      DP_STEP(sb + q)
    }
    // raw barrier (T4, r11-proven): drain LDS only; global loads stay in flight
    asm volatile("s_waitcnt lgkmcnt(0)\n\ts_barrier" ::: "memory");
  }
  { // epilogue: steps 800..814 (lane 255 finishes at c=511 exactly)
    int c0 = TOTM - W0 * w;
    float ringv = ring[w * 32 + ((c0 + (l & 15)) & 31)];
    #pragma unroll
    for (int q = 0; q < EPI; ++q) {
      float srq = __int_as_float(
          __builtin_amdgcn_readlane(__float_as_int(ringv), q));
      DP_STEP(TOTM + q)
    }
  }

  if (t == 255)
    loss[b] = aL1 * LN2;   // R[511][511]
}

// ======================= Fallback (round-1 kernel, tiny ws) =======================
#define DQ 16
#define YST 68

__device__ __forceinline__ void fb_step(
    const int d, const int t, const float4* __restrict__ xr, const float xx,
    const float* __restrict__ ylds,
    const float* __restrict__ a1, const float* __restrict__ a2,
    float* __restrict__ aw, float& myP1)
{
  const int j = d - t;
  const bool valid = (j >= 0) && (j < NN);
  float dd = 0.f;
  if (valid) {
    const float* yrow = &ylds[j * YST];
    float ax = 0.f, ay = 0.f, az = 0.f, aww = 0.f;
    #pragma unroll
    for (int k = 0; k < DQ; ++k) {
      float4 v = *(const float4*)(yrow + 4 * k);
      ax  = fmaf(xr[k].x, v.x, ax);
      ay  = fmaf(xr[k].y, v.y, ay);
      az  = fmaf(xr[k].z, v.z, az);
      aww = fmaf(xr[k].w, v.w, aww);
    }
    float dot = (ax + ay) + (az + aww);
    dd = fmaf(-2.f, dot, xx + yrow[DD]);
  }
  float p1m1 = a1[t];
  float p2m1 = a2[t];
  if (t == 0) p2m1 = (d == 0) ? 0.f : BIGF;
  float m = fminf(fminf(p2m1, p1m1), myP1);
  float s = __expf(m - p2m1) + __expf(m - p1m1) + __expf(m - myP1);
  float sm = m - __logf(s);
  float cur = valid ? (dd + sm) : BIGF;
  aw[t + 1] = cur;
  myP1 = cur;
  __syncthreads();
}

__global__ __launch_bounds__(512, 2)
void dtw_fallback_kernel(const float* __restrict__ X, const float* __restrict__ Y,
                         float* __restrict__ loss)
{
  __shared__ float ylds[NN * YST];
  __shared__ float diag[3][NN + 1];

  const int b = blockIdx.x;
  const int t = threadIdx.x;

  const float4* Y4 = (const float4*)(Y + (size_t)b * NN * DD);
  for (int idx = t; idx < NN * DQ; idx += NN) {
    float4 v = Y4[idx];
    *(float4*)&ylds[(idx >> 4) * YST + (idx & 15) * 4] = v;
  }
  diag[0][t + 1] = BIGF; diag[1][t + 1] = BIGF; diag[2][t + 1] = BIGF;
  if (t == 0) { diag[0][0] = BIGF; diag[1][0] = BIGF; diag[2][0] = BIGF; }
  __syncthreads();

  float4 xr[DQ];
  float xx = 0.f;
  const float4* X4 = (const float4*)(X + (size_t)b * NN * DD + (size_t)t * DD);
  #pragma unroll
  for (int k = 0; k < DQ; ++k) {
    float4 v = X4[k];
    xr[k] = v;
    xx += v.x * v.x + v.y * v.y + v.z * v.z + v.w * v.w;
  }
  {
    float s = 0.f;
    const float* yrow = &ylds[t * YST];
    #pragma unroll
    for (int k = 0; k < DQ; ++k) {
      float4 v = *(const float4*)(yrow + 4 * k);
      s += v.x * v.x + v.y * v.y + v.z * v.z + v.w * v.w;
    }
    ylds[t * YST + DD] = s;
  }
  __syncthreads();

  float myP1 = BIGF;
  for (int dbase = 0; dbase < 2 * NN - 1; dbase += 3) {
    fb_step(dbase,     t, xr, xx, ylds, diag[2], diag[1], diag[0], myP1);
    fb_step(dbase + 1, t, xr, xx, ylds, diag[0], diag[2], diag[1], myP1);
    fb_step(dbase + 2, t, xr, xx, ylds, diag[1], diag[0], diag[2], myP1);
  }
  if (t == NN - 1) loss[b] = myP1;
}

// ======================= mean =======================
__global__ void mean_kernel(const float* __restrict__ loss, float* __restrict__ out, int B)
{
  const int t = threadIdx.x;
  float v = (t < B) ? loss[t] : 0.f;
  #pragma unroll
  for (int off = 32; off; off >>= 1) v += __shfl_down(v, off);
  if (t == 0) out[0] = v / (float)B;
}

extern "C" void kernel_launch(void* const* d_in, const int* in_sizes, int n_in,
                              void* d_out, int out_size, void* d_ws, size_t ws_size,
                              hipStream_t stream)
{
  const float* X = (const float*)d_in[0];   // input  (x, DP rows i)
  const float* Y = (const float*)d_in[1];   // target (y, DP cols j)
  float* out = (float*)d_out;
  float* ws  = (float*)d_ws;

  const int B = in_sizes[0] / (NN * DD);    // 64

  const size_t S_bytes = (size_t)B * SROWS * 256 * 4;
  const size_t need = S_bytes + 256;

  if (ws_size >= need) {
    float*    loss = ws;                    // B floats
    unsigned* Sg   = (unsigned*)(ws + 64);  // 256B offset, [b][SROWS][256] half2
    // A = Y (j rows), B = X (i rows)
    delta_kernel<<<dim3(NN / TS, NN / TS, B), 256, 0, stream>>>(Y, X, Sg);
    dp_kernel<<<B, 256, 0, stream>>>((const __half2*)Sg, loss);
    mean_kernel<<<1, 64, 0, stream>>>(loss, out, B);
  } else {
    dtw_fallback_kernel<<<B, NN, 0, stream>>>(X, Y, ws);
    mean_kernel<<<1, 64, 0, stream>>>(ws, out, B);
  }
}